// Round 1
// baseline (445.422 us; speedup 1.0000x reference)
//
#include <hip/hip_runtime.h>
#include <stdint.h>

#define NB 16
#define NN 25200
#define NCLS 80
#define NROW 85
#define KPRE 1000
#define MAXDET 300
#define CONF_T 0.25f
#define IOU_T 0.45f
#define GCAP 8192

typedef unsigned long long u64;
typedef unsigned int u32;

// Descending-order sortable key: higher score -> smaller key. Exact for all
// finite floats; ties in score resolved later by index (stable argsort).
__device__ __forceinline__ u32 desc_key(float s) {
  u32 u = __float_as_uint(s);
  u = (u & 0x80000000u) ? ~u : (u | 0x80000000u);  // ascending orderable
  return ~u;                                        // descending
}

// ---------------- Kernel 1: decode ----------------
__global__ __launch_bounds__(256) void k_decode(
    const float* __restrict__ pred,
    float* __restrict__ scores, int* __restrict__ clsArr,
    float4* __restrict__ boxes) {
  int gid = blockIdx.x * blockDim.x + threadIdx.x;
  if (gid >= NB * NN) return;
  const float* p = pred + (size_t)gid * NROW;
  float px = p[0], py = p[1], pw = p[2], ph = p[3], obj = p[4];
  // conf = max_j fl(cls_j * obj); first-max argmax (matches jnp.argmax)
  float best = -1.0f;
  int bj = 0;
  for (int j = 0; j < NCLS; ++j) {
    float v = __fmul_rn(p[5 + j], obj);
    if (v > best) { best = v; bj = j; }
  }
  float score = (best > CONF_T) ? best : -1.0f;
  float hx = __fmul_rn(pw, 0.5f), hy = __fmul_rn(ph, 0.5f);
  float4 bx;
  bx.x = __fsub_rn(px, hx);
  bx.y = __fsub_rn(py, hy);
  bx.z = __fadd_rn(px, hx);
  bx.w = __fadd_rn(py, hy);
  scores[gid] = score;
  clsArr[gid] = bj;
  boxes[gid] = bx;
}

// ---------------- Kernel 2: exact top-1000 (sorted) per image ----------------
// 4x 8-bit radix refinement finds the exact 32-bit key threshold T such that
// count(key < T) < 1000 <= count(key <= T). Gather all key<=T (composite with
// idx), bitonic-sort in LDS, take first 1000. Reproduces stable argsort(-score).
__global__ __launch_bounds__(1024) void k_select(
    const float* __restrict__ scores, const int* __restrict__ clsArr,
    const float4* __restrict__ boxes,
    float* __restrict__ selScore, int* __restrict__ selCls,
    float4* __restrict__ selBox, float4* __restrict__ selOb,
    float* __restrict__ selArea) {
  int img = blockIdx.x;
  int tid = threadIdx.x;
  const float* sc = scores + (size_t)img * NN;

  extern __shared__ u64 smem[];
  u64* buf = smem;                    // GCAP u64 (64 KB)
  u32* hist = (u32*)(buf + GCAP);     // 256 u32
  __shared__ u32 sPrefix;
  __shared__ int sKr;
  __shared__ u32 sCount;

  u32 prefix = 0;
  int Kr = KPRE;
  for (int pass = 0; pass < 4; ++pass) {
    int shift = 24 - 8 * pass;
    if (tid < 256) hist[tid] = 0;
    __syncthreads();
    for (int n = tid; n < NN; n += 1024) {
      u32 k = desc_key(sc[n]);
      bool match = (pass == 0) || ((k >> (shift + 8)) == prefix);
      if (match) atomicAdd(&hist[(k >> shift) & 255], 1u);
    }
    __syncthreads();
    if (tid == 0) {
      u32 cum = 0, q = 0;
      for (q = 0; q < 256; ++q) {
        u32 h = hist[q];
        if (cum + h >= (u32)Kr) break;
        cum += h;
      }
      sPrefix = (prefix << 8) | q;
      sKr = Kr - (int)cum;
    }
    __syncthreads();
    prefix = sPrefix;
    Kr = sKr;
    __syncthreads();
  }
  u32 T = prefix;  // exact 32-bit threshold key

  if (tid == 0) sCount = 0;
  __syncthreads();
  for (int n = tid; n < NN; n += 1024) {
    u32 k = desc_key(sc[n]);
    if (k <= T) {
      u32 pos = atomicAdd(&sCount, 1u);
      if (pos < GCAP) buf[pos] = ((u64)k << 32) | (u32)n;
    }
  }
  __syncthreads();
  u32 cnt = sCount < GCAP ? sCount : GCAP;
  u32 M = 1024;
  while (M < cnt) M <<= 1;
  for (u32 i = cnt + tid; i < M; i += 1024) buf[i] = ~0ull;
  __syncthreads();

  // bitonic sort ascending over M elements
  for (u32 k = 2; k <= M; k <<= 1) {
    for (u32 j = k >> 1; j > 0; j >>= 1) {
      for (u32 i = tid; i < M; i += 1024) {
        u32 l = i ^ j;
        if (l > i) {
          u64 a = buf[i], b = buf[l];
          bool asc = ((i & k) == 0);
          bool sw = asc ? (a > b) : (a < b);
          if (sw) { buf[i] = b; buf[l] = a; }
        }
      }
      __syncthreads();
    }
  }

  if (tid < KPRE) {
    u64 e = buf[tid];
    u32 n = (u32)e;  // cnt >= KPRE guaranteed by construction
    float s = sc[n];
    int c = clsArr[(size_t)img * NN + n];
    float4 bx = boxes[(size_t)img * NN + n];
    int o = img * KPRE + tid;
    selScore[o] = s;
    selCls[o] = c;
    selBox[o] = bx;
    float off = __fmul_rn((float)c, 4096.0f);  // exact
    float4 ob;
    ob.x = __fadd_rn(bx.x, off);
    ob.y = __fadd_rn(bx.y, off);
    ob.z = __fadd_rn(bx.z, off);
    ob.w = __fadd_rn(bx.w, off);
    selOb[o] = ob;
    selArea[o] = __fmul_rn(__fsub_rn(ob.z, ob.x), __fsub_rn(ob.w, ob.y));
  }
}

// ---------------- Kernel 3: suppression scan + compaction ----------------
__global__ __launch_bounds__(1024) void k_nms(
    const float* __restrict__ selScore, const int* __restrict__ selCls,
    const float4* __restrict__ selBox, const float4* __restrict__ selOb,
    const float* __restrict__ selArea, float* __restrict__ out) {
  int img = blockIdx.x;
  int tid = threadIdx.x;
  extern __shared__ u64 smem[];
  u64* mask = smem;                          // KPRE*16 u64 = 128000 B
  float4* ob = (float4*)(mask + KPRE * 16);  // 16000 B
  float* area = (float*)(ob + KPRE);         // 4000 B
  __shared__ u64 aliveW[16];
  __shared__ int wPre[17];

  if (tid < KPRE) {
    ob[tid] = selOb[img * KPRE + tid];
    area[tid] = selArea[img * KPRE + tid];
  }
  __syncthreads();

  // Phase 1: thread i builds suppression row i (bits j>i with iou>thres)
  if (tid < KPRE) {
    float4 bi = ob[tid];
    float ai = area[tid];
    for (int w = 0; w < 16; ++w) {
      u64 m = 0;
      int jbase = w * 64;
      if (jbase + 63 > tid) {
        for (int b = 0; b < 64; ++b) {
          int j = jbase + b;
          if (j > tid && j < KPRE) {
            float4 bj = ob[j];
            float xx1 = fmaxf(bi.x, bj.x);
            float yy1 = fmaxf(bi.y, bj.y);
            float xx2 = fminf(bi.z, bj.z);
            float yy2 = fminf(bi.w, bj.w);
            float ww = fmaxf(__fsub_rn(xx2, xx1), 0.0f);
            float hh = fmaxf(__fsub_rn(yy2, yy1), 0.0f);
            float inter = __fmul_rn(ww, hh);
            // ((area_i + area_j) - inter) + 1e-9, then divide: exact ref order
            float den = __fadd_rn(__fsub_rn(__fadd_rn(ai, area[j]), inter), 1e-9f);
            float iou = __fdiv_rn(inter, den);
            if (iou > IOU_T) m |= (1ull << b);
          }
        }
      }
      mask[tid * 16 + w] = m;
    }
  }
  __syncthreads();

  // Phase 2: sequential scan on wave 0; lane w owns 64-bit word w
  if (tid < 64) {
    int lane = tid;
    int wl = lane & 15;
    u64 alive = 0;
    if (lane < 16) {
      for (int b = 0; b < 64; ++b) {
        int j = wl * 64 + b;
        if (j < KPRE && selScore[img * KPRE + j] > CONF_T) alive |= (1ull << b);
      }
    }
    for (int i0 = 0; i0 < KPRE; i0 += 8) {
      u64 m[8];
#pragma unroll
      for (int k = 0; k < 8; ++k) m[k] = mask[(i0 + k) * 16 + wl];
#pragma unroll
      for (int k = 0; k < 8; ++k) {
        int i = i0 + k;
        u64 aw = __shfl(alive, i >> 6, 64);
        if ((aw >> (i & 63)) & 1ull) alive &= ~m[k];
      }
    }
    if (lane < 16) aliveW[lane] = alive;
  }
  __syncthreads();

  if (tid == 0) {
    int c = 0;
    for (int w = 0; w < 16; ++w) {
      wPre[w] = c;
      c += __popcll(aliveW[w]);
    }
    wPre[16] = c;
  }
  __syncthreads();

  // Phase 3: zero this image's output, then write kept rows
  for (int t = tid; t < MAXDET * 6; t += 1024) out[(size_t)img * MAXDET * 6 + t] = 0.0f;
  __syncthreads();

  if (tid < KPRE) {
    int w = tid >> 6, b = tid & 63;
    u64 aw = aliveW[w];
    if ((aw >> b) & 1ull) {
      u64 lowmask = b ? (~0ull >> (64 - b)) : 0ull;
      int rank = wPre[w] + __popcll(aw & lowmask);
      if (rank < MAXDET) {
        float4 bx = selBox[img * KPRE + tid];
        float* o = out + ((size_t)img * MAXDET + rank) * 6;
        o[0] = bx.x;
        o[1] = bx.y;
        o[2] = bx.z;
        o[3] = bx.w;
        o[4] = selScore[img * KPRE + tid];
        o[5] = (float)selCls[img * KPRE + tid];
      }
    }
  }
}

extern "C" void kernel_launch(void* const* d_in, const int* in_sizes, int n_in,
                              void* d_out, int out_size, void* d_ws, size_t ws_size,
                              hipStream_t stream) {
  const float* pred = (const float*)d_in[0];
  char* ws = (char*)d_ws;
  size_t off = 0;
  float* scores = (float*)(ws + off); off += (size_t)NB * NN * 4;
  int* clsArr = (int*)(ws + off); off += (size_t)NB * NN * 4;
  float4* boxes = (float4*)(ws + off); off += (size_t)NB * NN * 16;
  float4* selBox = (float4*)(ws + off); off += (size_t)NB * KPRE * 16;
  float4* selOb = (float4*)(ws + off); off += (size_t)NB * KPRE * 16;
  float* selScore = (float*)(ws + off); off += (size_t)NB * KPRE * 4;
  int* selCls = (int*)(ws + off); off += (size_t)NB * KPRE * 4;
  float* selArea = (float*)(ws + off); off += (size_t)NB * KPRE * 4;
  if (off > ws_size) return;  // workspace too small: fail visibly

  float* outp = (float*)d_out;
  int total = NB * NN;
  k_decode<<<(total + 255) / 256, 256, 0, stream>>>(pred, scores, clsArr, boxes);
  k_select<<<NB, 1024, GCAP * 8 + 256 * 4, stream>>>(
      scores, clsArr, boxes, selScore, selCls, selBox, selOb, selArea);
  k_nms<<<NB, 1024, KPRE * 16 * 8 + KPRE * 16 + KPRE * 4, stream>>>(
      selScore, selCls, selBox, selOb, selArea, outp);
}

// Round 2
// 223.782 us; speedup vs baseline: 1.9904x; 1.9904x over previous
//
#include <hip/hip_runtime.h>
#include <stdint.h>

#define NB 16
#define NN 25200
#define NCLS 80
#define NROW 85
#define KPRE 1000
#define MAXDET 300
#define CONF_T 0.25f
#define IOU_T 0.45f
#define GCAP 8192
#define MROWS 1024  // padded mask rows per image

typedef unsigned long long u64;
typedef unsigned int u32;

// Descending-order sortable key: higher score -> smaller key. Ties in score
// resolved by index (stable argsort semantics).
__device__ __forceinline__ u32 desc_key(float s) {
  u32 u = __float_as_uint(s);
  u = (u & 0x80000000u) ? ~u : (u | 0x80000000u);
  return ~u;
}

// ---------------- Kernel 1: decode (vectorized loads) ----------------
__global__ __launch_bounds__(256) void k_decode(
    const float* __restrict__ pred,
    float* __restrict__ scores, int* __restrict__ clsArr,
    float4* __restrict__ boxes) {
  int gid = blockIdx.x * 256 + threadIdx.x;
  if (gid >= NB * NN) return;
  const float* p = pred + (size_t)gid * NROW;
  float4 b4;
  __builtin_memcpy(&b4, p, 16);  // x,y,w,h
  float4 c;
  __builtin_memcpy(&c, p + 4, 16);  // obj, cls0, cls1, cls2
  float obj = c.x;
  float best = -1.0f;
  int bj = 0;
  {
    float v = __fmul_rn(c.y, obj); if (v > best) { best = v; bj = 0; }
  }
  {
    float v = __fmul_rn(c.z, obj); if (v > best) { best = v; bj = 1; }
  }
  {
    float v = __fmul_rn(c.w, obj); if (v > best) { best = v; bj = 2; }
  }
#pragma unroll
  for (int k = 2; k < 21; ++k) {  // f[4k..4k+3] -> classes 4k-5..4k-2
    float4 q;
    __builtin_memcpy(&q, p + 4 * k, 16);
    int j0 = 4 * k - 5;
    float v0 = __fmul_rn(q.x, obj); if (v0 > best) { best = v0; bj = j0; }
    float v1 = __fmul_rn(q.y, obj); if (v1 > best) { best = v1; bj = j0 + 1; }
    float v2 = __fmul_rn(q.z, obj); if (v2 > best) { best = v2; bj = j0 + 2; }
    float v3 = __fmul_rn(q.w, obj); if (v3 > best) { best = v3; bj = j0 + 3; }
  }
  {
    float v = __fmul_rn(p[84], obj); if (v > best) { best = v; bj = 79; }
  }
  float score = (best > CONF_T) ? best : -1.0f;
  float hx = __fmul_rn(b4.z, 0.5f), hy = __fmul_rn(b4.w, 0.5f);
  float4 bx;
  bx.x = __fsub_rn(b4.x, hx);
  bx.y = __fsub_rn(b4.y, hy);
  bx.z = __fadd_rn(b4.x, hx);
  bx.w = __fadd_rn(b4.y, hy);
  scores[gid] = score;
  clsArr[gid] = bj;
  boxes[gid] = bx;
}

// ---------------- Kernel 2: exact top-1000 (sorted) per image ----------------
__global__ __launch_bounds__(1024) void k_select(
    const float* __restrict__ scores, const int* __restrict__ clsArr,
    const float4* __restrict__ boxes,
    float* __restrict__ selScore, int* __restrict__ selCls,
    float4* __restrict__ selBox, float4* __restrict__ selOb,
    float* __restrict__ selArea) {
  int img = blockIdx.x;
  int tid = threadIdx.x;
  const float* sc = scores + (size_t)img * NN;

  extern __shared__ u64 smem[];
  u64* buf = smem;                 // GCAP u64
  u32* hist = (u32*)(buf + GCAP);  // 256 u32
  __shared__ u32 sPrefix;
  __shared__ int sKr;
  __shared__ u32 sCount;

  u32 prefix = 0;
  int Kr = KPRE;
  for (int pass = 0; pass < 4; ++pass) {
    int shift = 24 - 8 * pass;
    if (tid < 256) hist[tid] = 0;
    __syncthreads();
    for (int n = tid; n < NN; n += 1024) {
      u32 k = desc_key(sc[n]);
      bool match = (pass == 0) || ((k >> (shift + 8)) == prefix);
      if (match) atomicAdd(&hist[(k >> shift) & 255], 1u);
    }
    __syncthreads();
    if (tid == 0) {
      u32 cum = 0, q = 0;
      for (q = 0; q < 256; ++q) {
        u32 h = hist[q];
        if (cum + h >= (u32)Kr) break;
        cum += h;
      }
      sPrefix = (prefix << 8) | q;
      sKr = Kr - (int)cum;
    }
    __syncthreads();
    prefix = sPrefix;
    Kr = sKr;
    __syncthreads();
  }
  u32 T = prefix;

  if (tid == 0) sCount = 0;
  __syncthreads();
  for (int n = tid; n < NN; n += 1024) {
    u32 k = desc_key(sc[n]);
    if (k <= T) {
      u32 pos = atomicAdd(&sCount, 1u);
      if (pos < GCAP) buf[pos] = ((u64)k << 32) | (u32)n;
    }
  }
  __syncthreads();
  u32 cnt = sCount < GCAP ? sCount : GCAP;
  u32 M = 1024;
  while (M < cnt) M <<= 1;
  for (u32 i = cnt + tid; i < M; i += 1024) buf[i] = ~0ull;
  __syncthreads();

  for (u32 k = 2; k <= M; k <<= 1) {
    for (u32 j = k >> 1; j > 0; j >>= 1) {
      for (u32 i = tid; i < M; i += 1024) {
        u32 l = i ^ j;
        if (l > i) {
          u64 a = buf[i], b = buf[l];
          bool asc = ((i & k) == 0);
          bool sw = asc ? (a > b) : (a < b);
          if (sw) { buf[i] = b; buf[l] = a; }
        }
      }
      __syncthreads();
    }
  }

  if (tid < KPRE) {
    u64 e = buf[tid];
    u32 n = (u32)e;
    float s = sc[n];
    int c = clsArr[(size_t)img * NN + n];
    float4 bx = boxes[(size_t)img * NN + n];
    int o = img * KPRE + tid;
    selScore[o] = s;
    selCls[o] = c;
    selBox[o] = bx;
    float off = __fmul_rn((float)c, 4096.0f);
    float4 ob;
    ob.x = __fadd_rn(bx.x, off);
    ob.y = __fadd_rn(bx.y, off);
    ob.z = __fadd_rn(bx.z, off);
    ob.w = __fadd_rn(bx.w, off);
    selOb[o] = ob;
    selArea[o] = __fmul_rn(__fsub_rn(ob.z, ob.x), __fsub_rn(ob.w, ob.y));
  }
}

// ---------------- Kernel 3: suppression mask build (128 blocks) ----------------
// Wave computes one 64-bit mask word per (row, word) task via ballot.
__global__ __launch_bounds__(1024) void k_mask(
    const float4* __restrict__ selOb, const float* __restrict__ selArea,
    u64* __restrict__ maskG) {
  int img = blockIdx.x >> 3;
  int sub = blockIdx.x & 7;
  int tid = threadIdx.x;
  int wid = tid >> 6, lane = tid & 63;
  __shared__ float4 ob[1024];
  __shared__ float area[1024];
  if (tid < KPRE) {
    ob[tid] = selOb[img * KPRE + tid];
    area[tid] = selArea[img * KPRE + tid];
  } else {
    ob[tid] = make_float4(0.f, 0.f, 0.f, 0.f);
    area[tid] = 0.f;
  }
  __syncthreads();

  int gw = sub * 16 + wid;  // 0..127 waves per image
  for (int i = gw; i < KPRE; i += 128) {
    float4 bi = ob[i];
    float ai = area[i];
    u64* mrow = maskG + ((size_t)img * MROWS + i) * 16;
    for (int w = i >> 6; w < 16; ++w) {
      int j = w * 64 + lane;
      float4 bb = ob[j];
      float aj = area[j];
      float xx1 = fmaxf(bi.x, bb.x);
      float yy1 = fmaxf(bi.y, bb.y);
      float xx2 = fminf(bi.z, bb.z);
      float yy2 = fminf(bi.w, bb.w);
      float ww = fmaxf(__fsub_rn(xx2, xx1), 0.0f);
      float hh = fmaxf(__fsub_rn(yy2, yy1), 0.0f);
      float inter = __fmul_rn(ww, hh);
      float den = __fadd_rn(__fsub_rn(__fadd_rn(ai, aj), inter), 1e-9f);
      // iou > T  <=>  inter > T*den   (den > 0)
      bool sup = (j > i) && (j < KPRE) && (inter > __fmul_rn(IOU_T, den));
      u64 bm = __ballot(sup);
      if (lane == 0) mrow[w] = bm;
    }
  }
}

// ---------------- Kernel 4: grouped sequential scan + compaction ----------------
__global__ __launch_bounds__(256) void k_scan(
    const u64* __restrict__ maskG,
    const float* __restrict__ selScore, const int* __restrict__ selCls,
    const float4* __restrict__ selBox, float* __restrict__ out) {
  int img = blockIdx.x;
  int tid = threadIdx.x;
  __shared__ u64 aliveW[16];
  __shared__ int wPre[17];

  if (tid >= 64) {
    for (int t = tid - 64; t < MAXDET * 6; t += 192)
      out[(size_t)img * MAXDET * 6 + t] = 0.0f;
  } else {
    int lane = tid;
    int wl = lane & 15;
    const u64* MB = maskG + (size_t)img * MROWS * 16;
    u64 supAcc = 0;
    for (int g = 0; g < 16; ++g) {
      int i0 = g * 64;
      float s = (i0 + lane < KPRE) ? selScore[img * KPRE + i0 + lane] : -1.0f;
      u64 aw = __ballot(s > CONF_T);
      u64 sg = __shfl(supAcc, g, 64);
      aw &= ~sg;
      bool use = (wl > g);
#pragma unroll
      for (int b8 = 0; b8 < 64; b8 += 8) {
        u64 mg[8], mv[8];
#pragma unroll
        for (int k = 0; k < 8; ++k) {
          const u64* r = MB + (size_t)(i0 + b8 + k) * 16;
          mg[k] = r[g];
          mv[k] = r[wl];
        }
#pragma unroll
        for (int k = 0; k < 8; ++k) {
          int b = b8 + k;
          u64 sel = (u64)0 - ((aw >> b) & 1ull);
          aw &= ~(mg[k] & sel);
          supAcc |= use ? (mv[k] & sel) : 0ull;
        }
      }
      if (lane == 0) aliveW[g] = aw;
    }
  }
  __syncthreads();

  if (tid == 0) {
    int c = 0;
    for (int w = 0; w < 16; ++w) {
      wPre[w] = c;
      c += __popcll(aliveW[w]);
    }
    wPre[16] = c;
  }
  __syncthreads();

  for (int i = tid; i < KPRE; i += 256) {
    int w = i >> 6, b = i & 63;
    u64 aw = aliveW[w];
    if ((aw >> b) & 1ull) {
      u64 lowmask = b ? (~0ull >> (64 - b)) : 0ull;
      int rank = wPre[w] + __popcll(aw & lowmask);
      if (rank < MAXDET) {
        float4 bx = selBox[img * KPRE + i];
        float* o = out + ((size_t)img * MAXDET + rank) * 6;
        o[0] = bx.x;
        o[1] = bx.y;
        o[2] = bx.z;
        o[3] = bx.w;
        o[4] = selScore[img * KPRE + i];
        o[5] = (float)selCls[img * KPRE + i];
      }
    }
  }
}

extern "C" void kernel_launch(void* const* d_in, const int* in_sizes, int n_in,
                              void* d_out, int out_size, void* d_ws, size_t ws_size,
                              hipStream_t stream) {
  const float* pred = (const float*)d_in[0];
  char* ws = (char*)d_ws;
  size_t off = 0;
  float* scores = (float*)(ws + off); off += (size_t)NB * NN * 4;
  int* clsArr = (int*)(ws + off); off += (size_t)NB * NN * 4;
  float4* boxes = (float4*)(ws + off);
  u64* maskG = (u64*)(ws + off);  // aliases boxes: boxes dead after k_select
  off += (size_t)NB * NN * 16;
  float4* selBox = (float4*)(ws + off); off += (size_t)NB * KPRE * 16;
  float4* selOb = (float4*)(ws + off); off += (size_t)NB * KPRE * 16;
  float* selScore = (float*)(ws + off); off += (size_t)NB * KPRE * 4;
  int* selCls = (int*)(ws + off); off += (size_t)NB * KPRE * 4;
  float* selArea = (float*)(ws + off); off += (size_t)NB * KPRE * 4;
  if (off > ws_size) return;

  float* outp = (float*)d_out;
  int total = NB * NN;
  k_decode<<<(total + 255) / 256, 256, 0, stream>>>(pred, scores, clsArr, boxes);
  k_select<<<NB, 1024, GCAP * 8 + 256 * 4, stream>>>(
      scores, clsArr, boxes, selScore, selCls, selBox, selOb, selArea);
  k_mask<<<NB * 8, 1024, 0, stream>>>(selOb, selArea, maskG);
  k_scan<<<NB, 256, 0, stream>>>(maskG, selScore, selCls, selBox, outp);
}

// Round 3
// 143.004 us; speedup vs baseline: 3.1148x; 1.5649x over previous
//
#include <hip/hip_runtime.h>
#include <stdint.h>

#define NB 16
#define NN 25200
#define NCLS 80
#define NROW 85
#define KPRE 1000
#define MAXDET 300
#define CONF_T 0.25f
#define IOU_T 0.45f
#define GCAP 8192
#define MROWS 1024  // padded mask rows per image

typedef unsigned long long u64;
typedef unsigned int u32;

// Descending-order sortable key: higher score -> smaller key. Ties in score
// resolved by index (stable argsort semantics).
__device__ __forceinline__ u32 desc_key(float s) {
  u32 u = __float_as_uint(s);
  u = (u & 0x80000000u) ? ~u : (u | 0x80000000u);
  return ~u;
}

// ---------------- Kernel 1: decode (vectorized loads) ----------------
__global__ __launch_bounds__(256) void k_decode(
    const float* __restrict__ pred,
    float* __restrict__ scores, int* __restrict__ clsArr,
    float4* __restrict__ boxes) {
  int gid = blockIdx.x * 256 + threadIdx.x;
  if (gid >= NB * NN) return;
  const float* p = pred + (size_t)gid * NROW;
  float4 b4;
  __builtin_memcpy(&b4, p, 16);  // x,y,w,h
  float4 c;
  __builtin_memcpy(&c, p + 4, 16);  // obj, cls0, cls1, cls2
  float obj = c.x;
  float best = -1.0f;
  int bj = 0;
  {
    float v = __fmul_rn(c.y, obj); if (v > best) { best = v; bj = 0; }
  }
  {
    float v = __fmul_rn(c.z, obj); if (v > best) { best = v; bj = 1; }
  }
  {
    float v = __fmul_rn(c.w, obj); if (v > best) { best = v; bj = 2; }
  }
#pragma unroll
  for (int k = 2; k < 21; ++k) {  // f[4k..4k+3] -> classes 4k-5..4k-2
    float4 q;
    __builtin_memcpy(&q, p + 4 * k, 16);
    int j0 = 4 * k - 5;
    float v0 = __fmul_rn(q.x, obj); if (v0 > best) { best = v0; bj = j0; }
    float v1 = __fmul_rn(q.y, obj); if (v1 > best) { best = v1; bj = j0 + 1; }
    float v2 = __fmul_rn(q.z, obj); if (v2 > best) { best = v2; bj = j0 + 2; }
    float v3 = __fmul_rn(q.w, obj); if (v3 > best) { best = v3; bj = j0 + 3; }
  }
  {
    float v = __fmul_rn(p[84], obj); if (v > best) { best = v; bj = 79; }
  }
  float score = (best > CONF_T) ? best : -1.0f;
  float hx = __fmul_rn(b4.z, 0.5f), hy = __fmul_rn(b4.w, 0.5f);
  float4 bx;
  bx.x = __fsub_rn(b4.x, hx);
  bx.y = __fsub_rn(b4.y, hy);
  bx.z = __fadd_rn(b4.x, hx);
  bx.w = __fadd_rn(b4.y, hy);
  scores[gid] = score;
  clsArr[gid] = bj;
  boxes[gid] = bx;
}

// ---------------- Kernel 2: exact top-1000 (sorted) per image ----------------
__global__ __launch_bounds__(1024) void k_select(
    const float* __restrict__ scores, const int* __restrict__ clsArr,
    const float4* __restrict__ boxes,
    float* __restrict__ selScore, int* __restrict__ selCls,
    float4* __restrict__ selBox, float4* __restrict__ selOb,
    float* __restrict__ selArea) {
  int img = blockIdx.x;
  int tid = threadIdx.x;
  const float* sc = scores + (size_t)img * NN;

  extern __shared__ u64 smem[];
  u64* buf = smem;                 // GCAP u64
  u32* hist = (u32*)(buf + GCAP);  // 256 u32
  __shared__ u32 sPrefix;
  __shared__ int sKr;
  __shared__ u32 sCount;

  u32 prefix = 0;
  int Kr = KPRE;
  for (int pass = 0; pass < 4; ++pass) {
    int shift = 24 - 8 * pass;
    if (tid < 256) hist[tid] = 0;
    __syncthreads();
    for (int n = tid; n < NN; n += 1024) {
      u32 k = desc_key(sc[n]);
      bool match = (pass == 0) || ((k >> (shift + 8)) == prefix);
      if (match) atomicAdd(&hist[(k >> shift) & 255], 1u);
    }
    __syncthreads();
    if (tid == 0) {
      u32 cum = 0, q = 0;
      for (q = 0; q < 256; ++q) {
        u32 h = hist[q];
        if (cum + h >= (u32)Kr) break;
        cum += h;
      }
      sPrefix = (prefix << 8) | q;
      sKr = Kr - (int)cum;
    }
    __syncthreads();
    prefix = sPrefix;
    Kr = sKr;
    __syncthreads();
  }
  u32 T = prefix;

  if (tid == 0) sCount = 0;
  __syncthreads();
  for (int n = tid; n < NN; n += 1024) {
    u32 k = desc_key(sc[n]);
    if (k <= T) {
      u32 pos = atomicAdd(&sCount, 1u);
      if (pos < GCAP) buf[pos] = ((u64)k << 32) | (u32)n;
    }
  }
  __syncthreads();
  u32 cnt = sCount < GCAP ? sCount : GCAP;
  u32 M = 1024;
  while (M < cnt) M <<= 1;
  for (u32 i = cnt + tid; i < M; i += 1024) buf[i] = ~0ull;
  __syncthreads();

  for (u32 k = 2; k <= M; k <<= 1) {
    for (u32 j = k >> 1; j > 0; j >>= 1) {
      for (u32 i = tid; i < M; i += 1024) {
        u32 l = i ^ j;
        if (l > i) {
          u64 a = buf[i], b = buf[l];
          bool asc = ((i & k) == 0);
          bool sw = asc ? (a > b) : (a < b);
          if (sw) { buf[i] = b; buf[l] = a; }
        }
      }
      __syncthreads();
    }
  }

  if (tid < KPRE) {
    u64 e = buf[tid];
    u32 n = (u32)e;
    float s = sc[n];
    int c = clsArr[(size_t)img * NN + n];
    float4 bx = boxes[(size_t)img * NN + n];
    int o = img * KPRE + tid;
    selScore[o] = s;
    selCls[o] = c;
    selBox[o] = bx;
    float off = __fmul_rn((float)c, 4096.0f);
    float4 ob;
    ob.x = __fadd_rn(bx.x, off);
    ob.y = __fadd_rn(bx.y, off);
    ob.z = __fadd_rn(bx.z, off);
    ob.w = __fadd_rn(bx.w, off);
    selOb[o] = ob;
    selArea[o] = __fmul_rn(__fsub_rn(ob.z, ob.x), __fsub_rn(ob.w, ob.y));
  }
}

// ---------------- Kernel 3: suppression mask build (128 blocks) ----------------
// Wave computes one 64-bit mask word per (row, word) task via ballot.
// Also emits nzf[row] = 1 iff the row suppresses anything.
__global__ __launch_bounds__(1024) void k_mask(
    const float4* __restrict__ selOb, const float* __restrict__ selArea,
    u64* __restrict__ maskG, u32* __restrict__ nzf) {
  int img = blockIdx.x >> 3;
  int sub = blockIdx.x & 7;
  int tid = threadIdx.x;
  int wid = tid >> 6, lane = tid & 63;
  __shared__ float4 ob[1024];
  __shared__ float area[1024];
  if (tid < KPRE) {
    ob[tid] = selOb[img * KPRE + tid];
    area[tid] = selArea[img * KPRE + tid];
  } else {
    ob[tid] = make_float4(0.f, 0.f, 0.f, 0.f);
    area[tid] = 0.f;
  }
  __syncthreads();

  int gw = sub * 16 + wid;  // 0..127 waves per image
  for (int i = gw; i < KPRE; i += 128) {
    float4 bi = ob[i];
    float ai = area[i];
    u64* mrow = maskG + ((size_t)img * MROWS + i) * 16;
    u64 rowAny = 0;
    for (int w = i >> 6; w < 16; ++w) {
      int j = w * 64 + lane;
      float4 bb = ob[j];
      float aj = area[j];
      float xx1 = fmaxf(bi.x, bb.x);
      float yy1 = fmaxf(bi.y, bb.y);
      float xx2 = fminf(bi.z, bb.z);
      float yy2 = fminf(bi.w, bb.w);
      float ww = fmaxf(__fsub_rn(xx2, xx1), 0.0f);
      float hh = fmaxf(__fsub_rn(yy2, yy1), 0.0f);
      float inter = __fmul_rn(ww, hh);
      float den = __fadd_rn(__fsub_rn(__fadd_rn(ai, aj), inter), 1e-9f);
      // iou > T  <=>  inter > T*den   (den > 0)
      bool sup = (j > i) && (j < KPRE) && (inter > __fmul_rn(IOU_T, den));
      u64 bm = __ballot(sup);
      rowAny |= bm;
      if (lane == 0) mrow[w] = bm;
    }
    if (lane == 0) nzf[(size_t)img * MROWS + i] = (rowAny != 0) ? 1u : 0u;
  }
}

// ---------------- Kernel 4: frontier scan + compaction ----------------
// Sequential semantics: for i ascending, if alive[i]: alive &= ~mask[i].
// Zero-mask rows are no-ops -> only iterate alive rows with nzf set, min-first
// (masks only clear higher indices, so min-first == sequential order).
__global__ __launch_bounds__(256) void k_scan(
    const u64* __restrict__ maskG, const u32* __restrict__ nzf,
    const float* __restrict__ selScore, const int* __restrict__ selCls,
    const float4* __restrict__ selBox, float* __restrict__ out) {
  int img = blockIdx.x;
  int tid = threadIdx.x;
  __shared__ u64 aliveW[16];
  __shared__ int wPre[17];

  if (tid >= 64) {
    for (int t = tid - 64; t < MAXDET * 6; t += 192)
      out[(size_t)img * MAXDET * 6 + t] = 0.0f;
  } else {
    int lane = tid;
    const u64* MB = maskG + (size_t)img * MROWS * 16;
    u64 alive = 0, nz = 0;
    for (int g = 0; g < 16; ++g) {
      int i = g * 64 + lane;
      bool v = (i < KPRE) && (selScore[img * KPRE + i] > CONF_T);
      bool nb = (i < KPRE) && (nzf[(size_t)img * MROWS + i] != 0);
      u64 bv = __ballot(v);
      u64 bn = __ballot(nb);
      if (lane == g) { alive = bv; nz = bn; }
    }
    u64 pending = (lane < 16) ? (alive & nz) : 0;
    while (true) {
      u64 ne = __ballot(pending != 0);
      if (ne == 0) break;
      int w0 = __ffsll(ne) - 1;
      u64 pw = __shfl(pending, w0, 64);
      int local = __ffsll(pw) - 1;
      int i = w0 * 64 + local;
      // mask row i: words < i>>6 were never written -> treat as 0
      u64 m = (lane < 16 && lane >= (i >> 6)) ? MB[(size_t)i * 16 + lane] : 0;
      alive &= ~m;
      pending &= ~m;
      if (lane == w0) pending &= ~(1ull << local);
    }
    if (lane < 16) aliveW[lane] = alive;
  }
  __syncthreads();

  if (tid == 0) {
    int c = 0;
    for (int w = 0; w < 16; ++w) {
      wPre[w] = c;
      c += __popcll(aliveW[w]);
    }
    wPre[16] = c;
  }
  __syncthreads();

  for (int i = tid; i < KPRE; i += 256) {
    int w = i >> 6, b = i & 63;
    u64 aw = aliveW[w];
    if ((aw >> b) & 1ull) {
      u64 lowmask = b ? (~0ull >> (64 - b)) : 0ull;
      int rank = wPre[w] + __popcll(aw & lowmask);
      if (rank < MAXDET) {
        float4 bx = selBox[img * KPRE + i];
        float* o = out + ((size_t)img * MAXDET + rank) * 6;
        o[0] = bx.x;
        o[1] = bx.y;
        o[2] = bx.z;
        o[3] = bx.w;
        o[4] = selScore[img * KPRE + i];
        o[5] = (float)selCls[img * KPRE + i];
      }
    }
  }
}

extern "C" void kernel_launch(void* const* d_in, const int* in_sizes, int n_in,
                              void* d_out, int out_size, void* d_ws, size_t ws_size,
                              hipStream_t stream) {
  const float* pred = (const float*)d_in[0];
  char* ws = (char*)d_ws;
  size_t off = 0;
  float* scores = (float*)(ws + off); off += (size_t)NB * NN * 4;
  int* clsArr = (int*)(ws + off); off += (size_t)NB * NN * 4;
  char* boxRegion = ws + off;
  float4* boxes = (float4*)boxRegion;
  u64* maskG = (u64*)boxRegion;  // aliases boxes: boxes dead after k_select
  // mask uses NB*MROWS*16*8 = 2 MB of the 6.45 MB region; nzf in the tail
  u32* nzf = (u32*)(boxRegion + (size_t)NB * MROWS * 16 * 8);
  off += (size_t)NB * NN * 16;
  float4* selBox = (float4*)(ws + off); off += (size_t)NB * KPRE * 16;
  float4* selOb = (float4*)(ws + off); off += (size_t)NB * KPRE * 16;
  float* selScore = (float*)(ws + off); off += (size_t)NB * KPRE * 4;
  int* selCls = (int*)(ws + off); off += (size_t)NB * KPRE * 4;
  float* selArea = (float*)(ws + off); off += (size_t)NB * KPRE * 4;
  if (off > ws_size) return;

  float* outp = (float*)d_out;
  int total = NB * NN;
  k_decode<<<(total + 255) / 256, 256, 0, stream>>>(pred, scores, clsArr, boxes);
  k_select<<<NB, 1024, GCAP * 8 + 256 * 4, stream>>>(
      scores, clsArr, boxes, selScore, selCls, selBox, selOb, selArea);
  k_mask<<<NB * 8, 1024, 0, stream>>>(selOb, selArea, maskG, nzf);
  k_scan<<<NB, 256, 0, stream>>>(maskG, nzf, selScore, selCls, selBox, outp);
}

// Round 4
// 122.326 us; speedup vs baseline: 3.6413x; 1.1690x over previous
//
#include <hip/hip_runtime.h>
#include <stdint.h>

#define NB 16
#define NN 25200
#define NCLS 80
#define NROW 85
#define KPRE 1000
#define MAXDET 300
#define CONF_T 0.25f
#define IOU_T 0.45f
#define GCAP 4096

typedef unsigned long long u64;
typedef unsigned int u32;
typedef unsigned char u8;

// Descending-order sortable key: higher score -> smaller key; ties by index.
__device__ __forceinline__ u32 desc_key(float s) {
  u32 u = __float_as_uint(s);
  u = (u & 0x80000000u) ? ~u : (u | 0x80000000u);
  return ~u;
}
__device__ __forceinline__ float inv_key(u32 k) {
  u32 u = ~k;
  u32 o = (u & 0x80000000u) ? (u & 0x7fffffffu) : ~u;
  return __uint_as_float(o);
}

// ---------------- Kernel 1: decode (LDS-staged coalesced) ----------------
// Block=256 (4 waves). Each wave: 64 rows in 4 chunks of 16 rows.
// Staging: fully-coalesced dwordx4 into per-wave LDS region.
// Processing: 4 lanes per row, 20 classes each, shfl-merge (first-max).
__global__ __launch_bounds__(256) void k_decode(
    const float* __restrict__ pred, float* __restrict__ scores,
    int* __restrict__ clsArr, float4* __restrict__ boxes) {
  __shared__ __align__(16) float lds[4][1360];
  const int wid = threadIdx.x >> 6, lane = threadIdx.x & 63;
  const int q = lane & 3, rl = lane >> 2;
  float* L = lds[wid];
  const int waveRow0 = blockIdx.x * 256 + wid * 64;
  for (int c = 0; c < 4; ++c) {
    const int row0 = waveRow0 + c * 16;
    const float* src = pred + (size_t)row0 * NROW;
#pragma unroll
    for (int k = 0; k < 5; ++k) {
      float4 v;
      __builtin_memcpy(&v, src + k * 256 + lane * 4, 16);
      *(float4*)(L + k * 256 + lane * 4) = v;
    }
    if (lane < 20) {
      float4 v;
      __builtin_memcpy(&v, src + 1280 + lane * 4, 16);
      *(float4*)(L + 1280 + lane * 4) = v;
    }
    __syncthreads();  // fence: LDS writes drained before cross-lane reads
    const float* R = L + rl * 85;
    float obj = R[4];
    float best = -1.0f;
    int bj = 0;
    const int j0 = q * 20;
#pragma unroll
    for (int jj = 0; jj < 20; ++jj) {
      float v = __fmul_rn(R[5 + j0 + jj], obj);
      if (v > best) { best = v; bj = j0 + jj; }
    }
    // merge quarters: larger value wins; tie -> smaller class index (jnp.argmax)
#pragma unroll
    for (int d = 1; d < 4; d <<= 1) {
      float b2 = __shfl_xor(best, d, 64);
      int j2 = __shfl_xor(bj, d, 64);
      if (b2 > best || (b2 == best && j2 < bj)) { best = b2; bj = j2; }
    }
    if (q == 0) {
      int gid = row0 + rl;
      float x = R[0], y = R[1], w = R[2], h = R[3];
      float hx = __fmul_rn(w, 0.5f), hy = __fmul_rn(h, 0.5f);
      float4 bx;
      bx.x = __fsub_rn(x, hx);
      bx.y = __fsub_rn(y, hy);
      bx.z = __fadd_rn(x, hx);
      bx.w = __fadd_rn(y, hy);
      scores[gid] = (best > CONF_T) ? best : -1.0f;
      clsArr[gid] = bj;
      boxes[gid] = bx;
    }
    __syncthreads();
  }
}

// ---------------- Kernel 2: select + per-class NMS + output ----------------
// One block per image. 12-bit hist -> bucket of 1000th key -> gather -> bitonic
// sort (exact stable top-1000) -> sort by (cls,pos) -> per-class greedy NMS
// (cross-class IoU is exactly 0 due to the 4096 offset) -> rank + write.
__global__ __launch_bounds__(1024) void k_select_nms(
    const float* __restrict__ scores, const int* __restrict__ clsArr,
    const float4* __restrict__ boxes, float* __restrict__ out) {
  const int img = blockIdx.x;
  const int tid = threadIdx.x;
  const float* sc = scores + (size_t)img * NN;
  const size_t imgN = (size_t)img * NN;

  extern __shared__ __align__(16) char smem[];
  u64* buf = (u64*)smem;                  // 32768 B (GCAP u64)
  float* bX1 = (float*)(smem + 32768);    // 4000 B each
  float* bY1 = bX1 + KPRE;
  float* bX2 = bY1 + KPRE;
  float* bY2 = bX2 + KPRE;
  char* ru = smem + 48768;                // reuse region (16384 B)
  u32* hist = (u32*)ru;                   // phase A: 4096 u32
  u32* s2 = (u32*)ru;                     // phase C+: 1024 u32
  u32* clsL = (u32*)(ru + 4096);          // 1000 u32
  u8* alive = (u8*)(ru + 8192);           // 1024 u8
  int* segS = (int*)(ru + 9216);          // 80 int
  int* segE = (int*)(ru + 9536);          // 80 int
  __shared__ u32 sB, sCnt;
  __shared__ u64 aliveW[16];
  __shared__ int wPre[16];

  // ---- Phase A: 12-bit histogram of desc keys ----
  for (int t = tid; t < 4096; t += 1024) hist[t] = 0;
  __syncthreads();
  const u32 INVB = desc_key(-1.0f) >> 20;  // bucket of all invalid scores
  for (int n = tid; n < NN; n += 1024) {
    float s = sc[n];
    bool inv = (s == -1.0f);
    u64 bb = __ballot(inv);
    if ((tid & 63) == 0 && bb) atomicAdd(&hist[INVB], (u32)__popcll(bb));
    if (!inv) atomicAdd(&hist[desc_key(s) >> 20], 1u);
  }
  __syncthreads();

  // ---- Phase B: prefix-scan, find bucket B containing the 1000th key ----
  u32 h0 = hist[tid * 4], h1 = hist[tid * 4 + 1], h2 = hist[tid * 4 + 2],
      h3 = hist[tid * 4 + 3];
  u32 s4 = h0 + h1 + h2 + h3;
  u32* scan = (u32*)buf;
  scan[tid] = s4;
  __syncthreads();
  for (int o = 1; o < 1024; o <<= 1) {
    u32 add = (tid >= o) ? scan[tid - o] : 0;
    __syncthreads();
    scan[tid] += add;
    __syncthreads();
  }
  u32 P = scan[tid] - s4;  // exclusive prefix
  if (P < KPRE && P + s4 >= KPRE) {
    u32 cacc = P;
    u32 b = 3;
    if (cacc + h0 >= KPRE) b = 0;
    else { cacc += h0;
      if (cacc + h1 >= KPRE) b = 1;
      else { cacc += h1;
        if (cacc + h2 >= KPRE) b = 2;
      }
    }
    sB = tid * 4 + b;
    sCnt = 0;
  }
  __syncthreads();
  const u32 B = sB;

  // ---- Phase C: gather all keys in buckets <= B ----
  for (int n = tid; n < NN; n += 1024) {
    u32 k = desc_key(sc[n]);
    if ((k >> 20) <= B) {
      u32 pos = atomicAdd(&sCnt, 1u);
      if (pos < GCAP) buf[pos] = ((u64)k << 32) | (u32)n;
    }
  }
  __syncthreads();
  u32 cnt = sCnt < GCAP ? sCnt : GCAP;
  u32 M = 1024;
  while (M < cnt) M <<= 1;
  for (u32 i = cnt + tid; i < M; i += 1024) buf[i] = ~0ull;
  __syncthreads();

  // ---- Phase D: bitonic sort ascending (key, idx) -> stable top-1000 ----
  for (u32 k = 2; k <= M; k <<= 1) {
    for (u32 j = k >> 1; j > 0; j >>= 1) {
      for (u32 i = tid; i < M; i += 1024) {
        u32 l = i ^ j;
        if (l > i) {
          u64 a = buf[i], b = buf[l];
          bool asc = ((i & k) == 0);
          if (asc ? (a > b) : (a < b)) { buf[i] = b; buf[l] = a; }
        }
      }
      __syncthreads();
    }
  }

  // ---- Phase E: fetch winners into LDS SoA ----
  if (tid < NCLS) { segS[tid] = 0; segE[tid] = 0; }
  if (tid < KPRE) {
    u32 n = (u32)buf[tid];
    int c = clsArr[imgN + n];
    float4 bx = boxes[imgN + n];
    bX1[tid] = bx.x; bY1[tid] = bx.y; bX2[tid] = bx.z; bY2[tid] = bx.w;
    clsL[tid] = (u32)c;
    float s = inv_key((u32)(buf[tid] >> 32));
    alive[tid] = (s > CONF_T) ? 1 : 0;
    s2[tid] = ((u32)c << 10) | (u32)tid;
  } else {
    alive[tid] = 0;
    s2[tid] = 0xFFFFFFFFu;
  }
  __syncthreads();

  // ---- Phase F: bitonic sort by (cls, pos) -> class-grouped, score order ----
  for (u32 k = 2; k <= 1024; k <<= 1) {
    for (u32 j = k >> 1; j > 0; j >>= 1) {
      u32 i = tid, l = i ^ j;
      if (l > i) {
        u32 a = s2[i], b = s2[l];
        bool asc = ((i & k) == 0);
        if (asc ? (a > b) : (a < b)) { s2[i] = b; s2[l] = a; }
      }
      __syncthreads();
    }
  }

  // ---- Phase G: class segment boundaries ----
  if (tid < KPRE) {
    u32 c = s2[tid] >> 10;
    u32 cp = (tid > 0) ? (s2[tid - 1] >> 10) : 0xFFFFFFFFu;
    if (c != cp) segS[c] = tid;
    u32 cn = (tid + 1 < KPRE) ? (s2[tid + 1] >> 10) : 0xFFFFFFFEu;
    if (c != cn) segE[c] = tid + 1;
  }
  __syncthreads();

  // ---- Phase H: per-class sequential greedy NMS (one wave per class) ----
  {
    const int lane = tid & 63, wid = tid >> 6;
    for (int c = wid; c < NCLS; c += 16) {
      int s = segS[c], e = segE[c];
      float off = __fmul_rn((float)c, 4096.0f);
      for (int i = s; i < e; ++i) {
        int ti = s2[i] & 1023;
        if (!alive[ti]) continue;  // uniform across wave
        float ix1 = __fadd_rn(bX1[ti], off), iy1 = __fadd_rn(bY1[ti], off);
        float ix2 = __fadd_rn(bX2[ti], off), iy2 = __fadd_rn(bY2[ti], off);
        float ia = __fmul_rn(__fsub_rn(ix2, ix1), __fsub_rn(iy2, iy1));
        for (int jb = i + 1 + lane; jb < e; jb += 64) {
          int tj = s2[jb] & 1023;
          float jx1 = __fadd_rn(bX1[tj], off), jy1 = __fadd_rn(bY1[tj], off);
          float jx2 = __fadd_rn(bX2[tj], off), jy2 = __fadd_rn(bY2[tj], off);
          float ja = __fmul_rn(__fsub_rn(jx2, jx1), __fsub_rn(jy2, jy1));
          float xx1 = fmaxf(ix1, jx1), yy1 = fmaxf(iy1, jy1);
          float xx2 = fminf(ix2, jx2), yy2 = fminf(iy2, jy2);
          float ww = fmaxf(__fsub_rn(xx2, xx1), 0.0f);
          float hh = fmaxf(__fsub_rn(yy2, yy1), 0.0f);
          float inter = __fmul_rn(ww, hh);
          float den = __fadd_rn(__fsub_rn(__fadd_rn(ia, ja), inter), 1e-9f);
          if (inter > __fmul_rn(IOU_T, den)) alive[tj] = 0;
        }
      }
    }
  }
  __syncthreads();

  // ---- Phase I: rank + write output ----
  float* outImg = out + (size_t)img * MAXDET * 6;
  for (int t = tid; t < MAXDET * 6; t += 1024) outImg[t] = 0.0f;
  if (tid < 64) {
    int lane = tid;
#pragma unroll
    for (int g = 0; g < 16; ++g) {
      u64 w = __ballot(alive[g * 64 + lane] != 0);
      if (lane == 0) aliveW[g] = w;
    }
  }
  __syncthreads();
  if (tid == 0) {
    int cacc = 0;
    for (int w = 0; w < 16; ++w) { wPre[w] = cacc; cacc += __popcll(aliveW[w]); }
  }
  __syncthreads();
  if (tid < KPRE) {
    int w = tid >> 6, b = tid & 63;
    u64 aw = aliveW[w];
    if ((aw >> b) & 1ull) {
      u64 lm = b ? (~0ull >> (64 - b)) : 0ull;
      int rank = wPre[w] + __popcll(aw & lm);
      if (rank < MAXDET) {
        float* o = outImg + (size_t)rank * 6;
        o[0] = bX1[tid];
        o[1] = bY1[tid];
        o[2] = bX2[tid];
        o[3] = bY2[tid];
        o[4] = inv_key((u32)(buf[tid] >> 32));
        o[5] = (float)clsL[tid];
      }
    }
  }
}

extern "C" void kernel_launch(void* const* d_in, const int* in_sizes, int n_in,
                              void* d_out, int out_size, void* d_ws, size_t ws_size,
                              hipStream_t stream) {
  const float* pred = (const float*)d_in[0];
  char* ws = (char*)d_ws;
  size_t off = 0;
  float* scores = (float*)(ws + off); off += (size_t)NB * NN * 4;
  int* clsArr = (int*)(ws + off); off += (size_t)NB * NN * 4;
  float4* boxes = (float4*)(ws + off); off += (size_t)NB * NN * 16;
  if (off > ws_size) return;

  float* outp = (float*)d_out;
  k_decode<<<NB * NN / 256, 256, 0, stream>>>(pred, scores, clsArr, boxes);
  k_select_nms<<<NB, 1024, 65536, stream>>>(scores, clsArr, boxes, outp);
}

// Round 5
// 100.391 us; speedup vs baseline: 4.4369x; 1.2185x over previous
//
#include <hip/hip_runtime.h>
#include <stdint.h>

#define NB 16
#define NN 25200
#define NCLS 80
#define NROW 85
#define KPRE 1000
#define MAXDET 300
#define CONF_T 0.25f
#define IOU_T 0.45f
#define GCAP 4096

typedef unsigned long long u64;
typedef unsigned int u32;
typedef unsigned char u8;

// Descending-order sortable key: higher score -> smaller key; ties by index.
__device__ __forceinline__ u32 desc_key(float s) {
  u32 u = __float_as_uint(s);
  u = (u & 0x80000000u) ? ~u : (u | 0x80000000u);
  return ~u;
}
__device__ __forceinline__ float inv_key(u32 k) {
  u32 u = ~k;
  u32 o = (u & 0x80000000u) ? (u & 0x7fffffffu) : ~u;
  return __uint_as_float(o);
}

// ---------------- Kernel 1: decode (LDS-staged coalesced) ----------------
__global__ __launch_bounds__(256) void k_decode(
    const float* __restrict__ pred, float* __restrict__ scores,
    int* __restrict__ clsArr, float4* __restrict__ boxes) {
  __shared__ __align__(16) float lds[4][1360];
  const int wid = threadIdx.x >> 6, lane = threadIdx.x & 63;
  const int q = lane & 3, rl = lane >> 2;
  float* L = lds[wid];
  const int waveRow0 = blockIdx.x * 256 + wid * 64;
  for (int c = 0; c < 4; ++c) {
    const int row0 = waveRow0 + c * 16;
    const float* src = pred + (size_t)row0 * NROW;
#pragma unroll
    for (int k = 0; k < 5; ++k) {
      float4 v;
      __builtin_memcpy(&v, src + k * 256 + lane * 4, 16);
      *(float4*)(L + k * 256 + lane * 4) = v;
    }
    if (lane < 20) {
      float4 v;
      __builtin_memcpy(&v, src + 1280 + lane * 4, 16);
      *(float4*)(L + 1280 + lane * 4) = v;
    }
    __syncthreads();
    const float* R = L + rl * 85;
    float obj = R[4];
    float best = -1.0f;
    int bj = 0;
    const int j0 = q * 20;
#pragma unroll
    for (int jj = 0; jj < 20; ++jj) {
      float v = __fmul_rn(R[5 + j0 + jj], obj);
      if (v > best) { best = v; bj = j0 + jj; }
    }
#pragma unroll
    for (int d = 1; d < 4; d <<= 1) {
      float b2 = __shfl_xor(best, d, 64);
      int j2 = __shfl_xor(bj, d, 64);
      if (b2 > best || (b2 == best && j2 < bj)) { best = b2; bj = j2; }
    }
    if (q == 0) {
      int gid = row0 + rl;
      float x = R[0], y = R[1], w = R[2], h = R[3];
      float hx = __fmul_rn(w, 0.5f), hy = __fmul_rn(h, 0.5f);
      float4 bx;
      bx.x = __fsub_rn(x, hx);
      bx.y = __fsub_rn(y, hy);
      bx.z = __fadd_rn(x, hx);
      bx.w = __fadd_rn(y, hy);
      scores[gid] = (best > CONF_T) ? best : -1.0f;
      clsArr[gid] = bj;
      boxes[gid] = bx;
    }
    __syncthreads();
  }
}

// ---------------- Kernel 2: per-image 12-bit histogram (wide) ----------------
__global__ __launch_bounds__(1024) void k_hist(const float* __restrict__ scores,
                                               u32* __restrict__ gHist) {
  const int img = blockIdx.x / 13, sub = blockIdx.x % 13;
  const int tid = threadIdx.x, lane = tid & 63;
  __shared__ u32 h[4096];
  for (int t = tid; t < 4096; t += 1024) h[t] = 0;
  __syncthreads();
  const float* sc = scores + (size_t)img * NN;
  const u32 INVB = desc_key(-1.0f) >> 20;
#pragma unroll
  for (int r = 0; r < 2; ++r) {
    int n = sub * 2048 + r * 1024 + tid;
    bool ok = (n < NN);
    float s = ok ? sc[n] : 0.0f;
    bool inv = ok && (s == -1.0f);
    u64 bb = __ballot(inv);
    if (lane == 0 && bb) atomicAdd(&h[INVB], (u32)__popcll(bb));
    if (ok && !inv) atomicAdd(&h[desc_key(s) >> 20], 1u);
  }
  __syncthreads();
  for (int t = tid; t < 4096; t += 1024) {
    u32 v = h[t];
    if (v) atomicAdd(&gHist[img * 4096 + t], v);
  }
}

// ---------------- Kernel 3: select + per-class NMS + output ----------------
__global__ __launch_bounds__(1024) void k_select_nms(
    const float* __restrict__ scores, const int* __restrict__ clsArr,
    const float4* __restrict__ boxes, const u32* __restrict__ gHist,
    float* __restrict__ out) {
  const int img = blockIdx.x;
  const int tid = threadIdx.x;
  const int lane = tid & 63;
  const float* sc = scores + (size_t)img * NN;
  const size_t imgN = (size_t)img * NN;

  extern __shared__ __align__(16) char smem[];
  u64* buf = (u64*)smem;                // 32768 B (GCAP u64)
  float* bX1 = (float*)(smem + 32768);  // 4 x 4000 B
  float* bY1 = bX1 + KPRE;
  float* bX2 = bY1 + KPRE;
  float* bY2 = bX2 + KPRE;
  // tail of buf (bytes 8192..32767) reused AFTER phase D (only buf[0..999] live)
  char* tail = smem + 8192;
  u64* cb = (u64*)tail;                  // 80*16 u64 = 10240 B class bitmaps
  u32* s2 = (u32*)(tail + 10240);        // 1024 u32
  u32* clsL = (u32*)(tail + 14336);      // 1000 u32
  u8* alive = (u8*)(tail + 18336);       // 1024 u8
  int* clsStart = (int*)(tail + 19360);  // 81 int
  __shared__ u32 subhist[256];
  __shared__ u32 sB, sKr, sCnt, sThr;
  __shared__ u64 aliveW[16];
  __shared__ int wPre[16];

  // ---- Phase P: prefetch all keys into registers (one latency) ----
  u32 kk[25];
#pragma unroll
  for (int t = 0; t < 25; ++t) {
    int n = tid + t * 1024;
    kk[t] = (n < NN) ? desc_key(sc[n]) : 0xFFFFFFFFu;
  }

  // ---- Phase A: load global hist, block prefix-scan, find bucket B ----
  u32 h0 = gHist[img * 4096 + tid * 4 + 0];
  u32 h1 = gHist[img * 4096 + tid * 4 + 1];
  u32 h2 = gHist[img * 4096 + tid * 4 + 2];
  u32 h3 = gHist[img * 4096 + tid * 4 + 3];
  u32 s4 = h0 + h1 + h2 + h3;
  u32* scan = (u32*)buf;
  scan[tid] = s4;
  __syncthreads();
  for (int o = 1; o < 1024; o <<= 1) {
    u32 add = (tid >= o) ? scan[tid - o] : 0;
    __syncthreads();
    scan[tid] += add;
    __syncthreads();
  }
  u32 P = scan[tid] - s4;  // exclusive prefix of this 4-bucket group
  if (P < KPRE && P + s4 >= KPRE) {
    u32 cacc = P;
    u32 b = 3;
    if (cacc + h0 >= KPRE) b = 0;
    else {
      cacc += h0;
      if (cacc + h1 >= KPRE) b = 1;
      else {
        cacc += h1;
        if (cacc + h2 >= KPRE) b = 2;
        else cacc += h2;
      }
    }
    sB = tid * 4 + b;
    sKr = KPRE - cacc;  // entries still needed inside bucket B (>=1)
    sCnt = 0;
  }
  __syncthreads();
  const u32 B = sB;
  const u32 Kr = sKr;

  // ---- Phase A2: 8-bit sub-histogram (bits 19..12) of bucket-B keys ----
  if (tid < 256) subhist[tid] = 0;
  __syncthreads();
#pragma unroll
  for (int t = 0; t < 25; ++t)
    if ((kk[t] >> 20) == B) atomicAdd(&subhist[(kk[t] >> 12) & 255], 1u);
  __syncthreads();
  u32 myc = (tid < 256) ? subhist[tid] : 0;
  for (int o = 1; o < 256; o <<= 1) {
    u32 add = (tid < 256 && tid >= o) ? subhist[tid - o] : 0;
    __syncthreads();
    if (tid < 256) subhist[tid] += add;
    __syncthreads();
  }
  if (tid < 256) {
    u32 inc = subhist[tid], exc = inc - myc;
    if (exc < Kr && inc >= Kr) sThr = (B << 8) | (u32)tid;  // 20-bit threshold
  }
  __syncthreads();
  const u32 thr = sThr;

  // ---- Phase C: gather keys with (k>>12) <= thr (wave-aggregated) ----
#pragma unroll
  for (int t = 0; t < 25; ++t) {
    bool g = (kk[t] >> 12) <= thr;
    u64 bb = __ballot(g);
    if (bb) {
      int ldr = __ffsll((long long)bb) - 1;
      u32 base = 0;
      if (lane == ldr) base = atomicAdd(&sCnt, (u32)__popcll(bb));
      base = __shfl(base, ldr, 64);
      if (g) {
        u32 pos = base + (u32)__popcll(bb & ((1ull << lane) - 1ull));
        if (pos < GCAP) buf[pos] = ((u64)kk[t] << 32) | (u32)(tid + t * 1024);
      }
    }
  }
  __syncthreads();
  u32 cnt = sCnt < GCAP ? sCnt : GCAP;  // expected ~= KPRE + few ties
  u32 M = 1024;
  while (M < cnt) M <<= 1;
  for (u32 i = cnt + tid; i < M; i += 1024) buf[i] = ~0ull;
  __syncthreads();

  // ---- Phase D: bitonic sort ascending (usually M=1024) ----
  for (u32 k = 2; k <= M; k <<= 1) {
    for (u32 j = k >> 1; j > 0; j >>= 1) {
      for (u32 i = tid; i < M; i += 1024) {
        u32 l = i ^ j;
        if (l > i) {
          u64 a = buf[i], b = buf[l];
          bool asc = ((i & k) == 0);
          if (asc ? (a > b) : (a < b)) { buf[i] = b; buf[l] = a; }
        }
      }
      __syncthreads();
    }
  }

  // ---- Phase E: fetch winners into LDS SoA; zero class bitmaps ----
  if (tid < KPRE) {
    u32 n = (u32)buf[tid];
    int c = clsArr[imgN + n];
    float4 bx = boxes[imgN + n];
    bX1[tid] = bx.x; bY1[tid] = bx.y; bX2[tid] = bx.z; bY2[tid] = bx.w;
    clsL[tid] = (u32)c;
    alive[tid] = (inv_key((u32)(buf[tid] >> 32)) > CONF_T) ? 1 : 0;
  } else {
    alive[tid] = 0;
  }
  for (int t = tid; t < NCLS * 16; t += 1024) cb[t] = 0;
  __syncthreads();

  // ---- Phase F: class grouping via bitmaps + counting scatter ----
  if (tid < KPRE) atomicOr(&cb[clsL[tid] * 16 + (tid >> 6)], 1ull << (tid & 63));
  __syncthreads();
  if (tid < NCLS) {
    int s = 0;
#pragma unroll
    for (int w = 0; w < 16; ++w) s += (int)__popcll(cb[tid * 16 + w]);
    subhist[tid] = (u32)s;  // class counts (subhist free now)
  }
  __syncthreads();
  if (tid == 0) {
    int acc = 0;
    for (int c = 0; c < NCLS; ++c) { clsStart[c] = acc; acc += (int)subhist[c]; }
    clsStart[NCLS] = acc;
  }
  __syncthreads();
  if (tid < KPRE) {
    int c = (int)clsL[tid];
    int w = tid >> 6;
    int p = clsStart[c];
    for (int w2 = 0; w2 < w; ++w2) p += (int)__popcll(cb[c * 16 + w2]);
    p += (int)__popcll(cb[c * 16 + w] & ((1ull << (tid & 63)) - 1ull));
    s2[p] = (u32)tid;
  }
  __syncthreads();

  // ---- Phase H: per-class sequential greedy NMS (one wave per class) ----
  {
    const int wid2 = tid >> 6;
    for (int c = wid2; c < NCLS; c += 16) {
      int s = clsStart[c], e = clsStart[c + 1];
      float offc = __fmul_rn((float)c, 4096.0f);
      for (int i = s; i < e; ++i) {
        int ti = (int)s2[i];
        if (!alive[ti]) continue;  // wave-uniform
        float ix1 = __fadd_rn(bX1[ti], offc), iy1 = __fadd_rn(bY1[ti], offc);
        float ix2 = __fadd_rn(bX2[ti], offc), iy2 = __fadd_rn(bY2[ti], offc);
        float ia = __fmul_rn(__fsub_rn(ix2, ix1), __fsub_rn(iy2, iy1));
        for (int jb = i + 1 + lane; jb < e; jb += 64) {
          int tj = (int)s2[jb];
          float jx1 = __fadd_rn(bX1[tj], offc), jy1 = __fadd_rn(bY1[tj], offc);
          float jx2 = __fadd_rn(bX2[tj], offc), jy2 = __fadd_rn(bY2[tj], offc);
          float ja = __fmul_rn(__fsub_rn(jx2, jx1), __fsub_rn(jy2, jy1));
          float xx1 = fmaxf(ix1, jx1), yy1 = fmaxf(iy1, jy1);
          float xx2 = fminf(ix2, jx2), yy2 = fminf(iy2, jy2);
          float ww = fmaxf(__fsub_rn(xx2, xx1), 0.0f);
          float hh = fmaxf(__fsub_rn(yy2, yy1), 0.0f);
          float inter = __fmul_rn(ww, hh);
          float den = __fadd_rn(__fsub_rn(__fadd_rn(ia, ja), inter), 1e-9f);
          if (inter > __fmul_rn(IOU_T, den)) alive[tj] = 0;
        }
      }
    }
  }
  __syncthreads();

  // ---- Phase I: rank + write output ----
  float* outImg = out + (size_t)img * MAXDET * 6;
  for (int t = tid; t < MAXDET * 6; t += 1024) outImg[t] = 0.0f;
  if (tid < 64) {
#pragma unroll
    for (int g = 0; g < 16; ++g) {
      u64 w = __ballot(alive[g * 64 + lane] != 0);
      if (lane == 0) aliveW[g] = w;
    }
  }
  __syncthreads();
  if (tid == 0) {
    int cacc = 0;
    for (int w = 0; w < 16; ++w) { wPre[w] = cacc; cacc += __popcll(aliveW[w]); }
  }
  __syncthreads();
  if (tid < KPRE) {
    int w = tid >> 6, b = tid & 63;
    u64 aw = aliveW[w];
    if ((aw >> b) & 1ull) {
      u64 lm = b ? (~0ull >> (64 - b)) : 0ull;
      int rank = wPre[w] + __popcll(aw & lm);
      if (rank < MAXDET) {
        float* o = outImg + (size_t)rank * 6;
        o[0] = bX1[tid];
        o[1] = bY1[tid];
        o[2] = bX2[tid];
        o[3] = bY2[tid];
        o[4] = inv_key((u32)(buf[tid] >> 32));
        o[5] = (float)clsL[tid];
      }
    }
  }
}

extern "C" void kernel_launch(void* const* d_in, const int* in_sizes, int n_in,
                              void* d_out, int out_size, void* d_ws, size_t ws_size,
                              hipStream_t stream) {
  const float* pred = (const float*)d_in[0];
  char* ws = (char*)d_ws;
  size_t off = 0;
  float* scores = (float*)(ws + off); off += (size_t)NB * NN * 4;
  int* clsArr = (int*)(ws + off); off += (size_t)NB * NN * 4;
  float4* boxes = (float4*)(ws + off); off += (size_t)NB * NN * 16;
  u32* gHist = (u32*)(ws + off); off += (size_t)NB * 4096 * 4;
  if (off > ws_size) return;

  float* outp = (float*)d_out;
  hipMemsetAsync(gHist, 0, (size_t)NB * 4096 * 4, stream);
  k_decode<<<NB * NN / 256, 256, 0, stream>>>(pred, scores, clsArr, boxes);
  k_hist<<<NB * 13, 1024, 0, stream>>>(scores, gHist);
  k_select_nms<<<NB, 1024, 48768, stream>>>(scores, clsArr, boxes, gHist, outp);
}